// Round 3
// baseline (168.127 us; speedup 1.0000x reference)
//
#include <hip/hip_runtime.h>

typedef __bf16 bf16x8 __attribute__((ext_vector_type(8)));
typedef float f32x4 __attribute__((ext_vector_type(4)));
typedef unsigned short u16;
typedef unsigned short u16x4 __attribute__((ext_vector_type(4)));
typedef unsigned short u16x8 __attribute__((ext_vector_type(8)));

#define MFMA16(a, b, c) __builtin_amdgcn_mfma_f32_16x16x32_bf16(a, b, c, 0, 0, 0)

__device__ __forceinline__ u16 f2bf(float f) {
    unsigned u = __builtin_bit_cast(unsigned, f);
    u += 0x7fffu + ((u >> 16) & 1u);   // RNE
    return (u16)(u >> 16);
}

__device__ __forceinline__ bf16x8 ld_frag(const u16* p) {
    u16x8 v = *(const u16x8*)p;
    return __builtin_bit_cast(bf16x8, v);
}

__device__ __forceinline__ u16x8 pack8(float4 a, float4 b) {
    u16x8 o = { f2bf(a.x), f2bf(a.y), f2bf(a.z), f2bf(a.w),
                f2bf(b.x), f2bf(b.y), f2bf(b.z), f2bf(b.w) };
    return o;
}

// ---------------------------------------------------------------------------
// wcvt: Wq|Wk|Wv fp32 -> Wb bf16 in MFMA B-fragment order.
// Wb u16 offset = ((c*3 + nt)*16 + f)*512 + l*8,  f = n16*2 + ks,
// element = W_nt[n16*16 + (l&15)][c*64 + ks*32 + (l>>4)*8 + j]
// ---------------------------------------------------------------------------
__global__ __launch_bounds__(256) void wcvt(
    const float* __restrict__ Wq, const float* __restrict__ Wk,
    const float* __restrict__ Wv, u16* __restrict__ Wb)
{
    int g = blockIdx.x * 256 + threadIdx.x;   // 49152 threads
    int l = g & 63;
    int f = (g >> 6) & 15;
    int idx = g >> 10;                        // c*3 + nt, 0..47
    int nt = idx % 3, c = idx / 3;
    int nrow = (f >> 1) * 16 + (l & 15);
    int k = c * 64 + (f & 1) * 32 + (l >> 4) * 8;
    const float* W = (nt == 0 ? Wq : nt == 1 ? Wk : Wv) + (size_t)nrow * 1024 + k;
    float4 a = *(const float4*)(W);
    float4 b = *(const float4*)(W + 4);
    *(u16x8*)(Wb + (size_t)g * 8) = pack8(a, b);
}

// ---------------------------------------------------------------------------
// qkv_fused: q|k|v = x @ W^T + b.  grid (3, 128): nt x m-tile(128).
// 4 waves, wave 64x64, BK=64. A (x, cvt bf16) via double-buffered LDS in
// fragment order; B straight from global Wb (frag order, L2-hot, no LDS).
// q stored natural [s][d]; k,v stored TRANSPOSED kT/vT[d][t] via LDS epilogue.
// ---------------------------------------------------------------------------
__global__ __launch_bounds__(256, 3) void qkv_fused(
    const float* __restrict__ x, const u16* __restrict__ Wb,
    const float* __restrict__ bq, const float* __restrict__ bk,
    const float* __restrict__ bv,
    u16* __restrict__ qo, u16* __restrict__ kT, u16* __restrict__ vT)
{
    __shared__ __align__(16) u16 As[17408];  // 2 bufs of 8704 (8192 used); epilogue uses all

    const int nt = blockIdx.x;
    const int m0 = blockIdx.y * 128;
    const int tid = threadIdx.x, lane = tid & 63, w = tid >> 6;
    const int quad = lane >> 4, l16 = lane & 15;
    const int wm = (w >> 1) * 64, wn = (w & 1) * 64;

    // A staging: thread -> (row = tid>>1, half = tid&1), 8 float4 = 128B run
    const int arow = tid >> 1, ahalf = tid & 1;
    const float* xp = x + (size_t)(m0 + arow) * 1024 + ahalf * 32;
    const int abase = ((arow >> 4) * 2 + ahalf) * 512 + (arow & 15) * 8;

    // B frags: global base for this nt; chunk c adds c*24576, frag f adds f*512
    const u16* wbase = Wb + (size_t)nt * 8192 + lane * 8;
    const int nfb = (wn >> 4);               // wave's first n16

    f32x4 acc[4][4] = {};

    // prologue: stage chunk 0 into buf 0
    {
        const float4* xv = (const float4*)xp;
        #pragma unroll
        for (int jj = 0; jj < 4; ++jj)
            *(u16x8*)&As[abase + jj * 128] = pack8(xv[jj * 2], xv[jj * 2 + 1]);
    }

    for (int c = 0; c < 16; ++c) {
        const int cur = c & 1;
        __syncthreads();

        // B fragment loads (global, frag-order)
        u16x8 braw[8];
        #pragma unroll
        for (int ni = 0; ni < 4; ++ni)
            #pragma unroll
            for (int ks = 0; ks < 2; ++ks)
                braw[ni * 2 + ks] = *(const u16x8*)(
                    wbase + (size_t)c * 24576 + ((nfb + ni) * 2 + ks) * 512);

        // A fragment loads (LDS identity, conflict-free)
        bf16x8 af[8];
        const u16* ab = As + cur * 8704 + lane * 8;
        #pragma unroll
        for (int mi = 0; mi < 4; ++mi)
            #pragma unroll
            for (int ks = 0; ks < 2; ++ks)
                af[mi * 2 + ks] = ld_frag(ab + (((wm >> 4) + mi) * 2 + ks) * 512);

        #pragma unroll
        for (int ks = 0; ks < 2; ++ks)
            #pragma unroll
            for (int mi = 0; mi < 4; ++mi)
                #pragma unroll
                for (int ni = 0; ni < 4; ++ni)
                    acc[mi][ni] = MFMA16(af[mi * 2 + ks],
                                         __builtin_bit_cast(bf16x8, braw[ni * 2 + ks]),
                                         acc[mi][ni]);

        // stage chunk c+1 into the other buffer
        if (c < 15) {
            const float4* xv = (const float4*)(xp + (c + 1) * 64);
            u16* aw = As + (cur ^ 1) * 8704 + abase;
            #pragma unroll
            for (int jj = 0; jj < 4; ++jj)
                *(u16x8*)&aw[jj * 128] = pack8(xv[jj * 2], xv[jj * 2 + 1]);
        }
    }

    __syncthreads();   // done with As as K-loop buffers
    const float* bias = nt == 0 ? bq : (nt == 1 ? bk : bv);

    if (nt == 0) {
        // Ep[t][d] stride 136, then coalesced natural store of q
        #pragma unroll
        for (int ni = 0; ni < 4; ++ni) {
            int d = wn + ni * 16 + l16;
            float bb = bias[d];
            #pragma unroll
            for (int mi = 0; mi < 4; ++mi)
                #pragma unroll
                for (int r = 0; r < 4; ++r)
                    As[(wm + mi * 16 + quad * 4 + r) * 136 + d] =
                        f2bf(acc[mi][ni][r] + bb);
        }
        __syncthreads();
        #pragma unroll
        for (int i = 0; i < 8; ++i) {
            int s = tid + i * 256;
            int tr = s >> 4, d8 = (s & 15) * 8;
            *(u16x8*)(qo + (size_t)(m0 + tr) * 128 + d8) =
                *(u16x8*)&As[tr * 136 + d8];
        }
    } else {
        // Ep[d][t] stride 136 (b64 vector writes), then coalesced kT/vT store
        u16* dstT = (nt == 1) ? kT : vT;
        #pragma unroll
        for (int ni = 0; ni < 4; ++ni) {
            int d = wn + ni * 16 + l16;
            float bb = bias[d];
            #pragma unroll
            for (int mi = 0; mi < 4; ++mi) {
                u16x4 v4 = { f2bf(acc[mi][ni][0] + bb), f2bf(acc[mi][ni][1] + bb),
                             f2bf(acc[mi][ni][2] + bb), f2bf(acc[mi][ni][3] + bb) };
                *(u16x4*)&As[d * 136 + wm + mi * 16 + quad * 4] = v4;
            }
        }
        __syncthreads();
        #pragma unroll
        for (int i = 0; i < 8; ++i) {
            int s = tid + i * 256;
            int d = s >> 4, t8 = (s & 15) * 8;
            *(u16x8*)(dstT + (size_t)d * 16384 + m0 + t8) =
                *(u16x8*)&As[d * 136 + t8];
        }
    }
}

// ---------------------------------------------------------------------------
// kt_v: partial T[e][d] = sum_t vT[e][t]*kT[d][t] over a 128-t chunk.
// grid (32, 4). Both operands t-contiguous -> vector staging, no transpose.
// ---------------------------------------------------------------------------
__global__ __launch_bounds__(256) void kt_v(
    const u16* __restrict__ kT, const u16* __restrict__ vT,
    float* __restrict__ part)
{
    __shared__ __align__(16) u16 vL[128 * 136];
    __shared__ __align__(16) u16 kL[128 * 136];

    const int c = blockIdx.x, b = blockIdx.y;
    const size_t g0 = (size_t)b * 4096 + c * 128;
    const int tid = threadIdx.x, lane = tid & 63, w = tid >> 6;
    const int quad = lane >> 4, l16 = lane & 15;
    const int we = (w >> 1) * 64, wd = (w & 1) * 64;

    #pragma unroll
    for (int i = 0; i < 8; ++i) {
        int s = tid + i * 256;
        int e = s >> 4, t8 = (s & 15) * 8;
        *(u16x8*)&vL[e * 136 + t8] = *(const u16x8*)(vT + (size_t)e * 16384 + g0 + t8);
        *(u16x8*)&kL[e * 136 + t8] = *(const u16x8*)(kT + (size_t)e * 16384 + g0 + t8);
    }
    __syncthreads();

    f32x4 acc[4][4] = {};
    #pragma unroll
    for (int ks = 0; ks < 4; ++ks) {
        bf16x8 af[4], bfr[4];
        #pragma unroll
        for (int mi = 0; mi < 4; ++mi)
            af[mi] = ld_frag(&vL[(we + mi * 16 + l16) * 136 + ks * 32 + quad * 8]);
        #pragma unroll
        for (int ni = 0; ni < 4; ++ni)
            bfr[ni] = ld_frag(&kL[(wd + ni * 16 + l16) * 136 + ks * 32 + quad * 8]);
        #pragma unroll
        for (int mi = 0; mi < 4; ++mi)
            #pragma unroll
            for (int ni = 0; ni < 4; ++ni)
                acc[mi][ni] = MFMA16(af[mi], bfr[ni], acc[mi][ni]);
    }

    float* dst = part + (size_t)(b * 32 + c) * 16384;
    #pragma unroll
    for (int mi = 0; mi < 4; ++mi)
        #pragma unroll
        for (int ni = 0; ni < 4; ++ni)
            #pragma unroll
            for (int r = 0; r < 4; ++r)
                dst[(we + mi * 16 + quad * 4 + r) * 128 + (wd + ni * 16 + l16)] =
                    acc[mi][ni][r];
}

// ---------------------------------------------------------------------------
// reduceT: 32 fp32 partials -> T bf16 [4][128][128], scale folded in.
// ---------------------------------------------------------------------------
__global__ __launch_bounds__(256) void reduceT(
    const float* __restrict__ part, u16* __restrict__ T)
{
    int gid = blockIdx.x * 256 + threadIdx.x;   // 0..65535
    int b = gid >> 14, idx = gid & 16383;
    const float* p = part + (size_t)b * 32 * 16384 + idx;
    float s = 0.f;
    #pragma unroll
    for (int c = 0; c < 32; ++c) s += p[(size_t)c * 16384];
    T[gid] = f2bf(s * 0.088388347648318447f);   // scale = 128^-0.5
}

// ---------------------------------------------------------------------------
// out_gemm: outT-form — C[e][s] with A=T[e][d], B=q[s][d] (both d-contig).
// C/D layout then gives out[s][e] as contiguous f32x4 runs: full-line stores.
// grid 256 (64-s tiles), 4 waves: wave e64 x s32.
// ---------------------------------------------------------------------------
__global__ __launch_bounds__(256) void out_gemm(
    const u16* __restrict__ qo, const u16* __restrict__ T,
    float* __restrict__ out)
{
    __shared__ __align__(16) u16 tL[128 * 136];
    __shared__ __align__(16) u16 qL[64 * 136];

    const int s0 = blockIdx.x * 64;
    const int b  = s0 >> 12;
    const int tid = threadIdx.x, lane = tid & 63, w = tid >> 6;
    const int quad = lane >> 4, l16 = lane & 15;
    const int we = (w >> 1) * 64, ws = (w & 1) * 32;

    #pragma unroll
    for (int i = 0; i < 8; ++i) {
        int s = tid + i * 256;
        int e = s >> 4, d8 = (s & 15) * 8;
        *(u16x8*)&tL[e * 136 + d8] = *(const u16x8*)(T + (size_t)b * 16384 + e * 128 + d8);
    }
    #pragma unroll
    for (int i = 0; i < 4; ++i) {
        int s = tid + i * 256;
        int sr = s >> 4, d8 = (s & 15) * 8;
        *(u16x8*)&qL[sr * 136 + d8] = *(const u16x8*)(qo + (size_t)(s0 + sr) * 128 + d8);
    }
    __syncthreads();

    f32x4 acc[4][2] = {};
    #pragma unroll
    for (int ks = 0; ks < 4; ++ks) {
        bf16x8 af[4], bfr[2];
        #pragma unroll
        for (int mi = 0; mi < 4; ++mi)
            af[mi] = ld_frag(&tL[(we + mi * 16 + l16) * 136 + ks * 32 + quad * 8]);
        #pragma unroll
        for (int ni = 0; ni < 2; ++ni)
            bfr[ni] = ld_frag(&qL[(ws + ni * 16 + l16) * 136 + ks * 32 + quad * 8]);
        #pragma unroll
        for (int mi = 0; mi < 4; ++mi)
            #pragma unroll
            for (int ni = 0; ni < 2; ++ni)
                acc[mi][ni] = MFMA16(af[mi], bfr[ni], acc[mi][ni]);
    }

    // store: col(l16) = s, rows = e run of 4 -> f32x4 contiguous in out[s][e]
    #pragma unroll
    for (int mi = 0; mi < 4; ++mi)
        #pragma unroll
        for (int ni = 0; ni < 2; ++ni) {
            int s = s0 + ws + ni * 16 + l16;
            int e0 = we + mi * 16 + quad * 4;
            *(f32x4*)(out + (size_t)s * 128 + e0) = acc[mi][ni];
        }
}

// ---------------------------------------------------------------------------
extern "C" void kernel_launch(void* const* d_in, const int* in_sizes, int n_in,
                              void* d_out, int out_size, void* d_ws, size_t ws_size,
                              hipStream_t stream)
{
    const float* x  = (const float*)d_in[0];
    const float* Wq = (const float*)d_in[1];
    const float* bq = (const float*)d_in[2];
    const float* Wk = (const float*)d_in[3];
    const float* bk = (const float*)d_in[4];
    const float* Wv = (const float*)d_in[5];
    const float* bv = (const float*)d_in[6];
    float* out = (float*)d_out;

    char* ws = (char*)d_ws;
    u16*   qo   = (u16*)(ws);                          //  4 MB, natural [s][d]
    u16*   kT   = (u16*)(ws + ((size_t)4 << 20));      //  4 MB, [d][t]
    u16*   vT   = (u16*)(ws + ((size_t)8 << 20));      //  4 MB, [e][t]
    // Wb (768 KB) aliases part (8 MB): Wb dead before kt_v writes part.
    u16*   Wb   = (u16*)(ws + ((size_t)12 << 20));
    float* part = (float*)(ws + ((size_t)12 << 20));
    u16*   T    = (u16*)(ws + ((size_t)20 << 20));     // 128 KB

    hipLaunchKernelGGL(wcvt, dim3(192), dim3(256), 0, stream, Wq, Wk, Wv, Wb);
    hipLaunchKernelGGL(qkv_fused, dim3(3, 128), dim3(256), 0, stream,
                       x, Wb, bq, bk, bv, qo, kT, vT);
    hipLaunchKernelGGL(kt_v, dim3(32, 4), dim3(256), 0, stream, kT, vT, part);
    hipLaunchKernelGGL(reduceT, dim3(256), dim3(256), 0, stream, part, T);
    hipLaunchKernelGGL(out_gemm, dim3(256), dim3(256), 0, stream, qo, T, out);
}

// Round 5
// 151.363 us; speedup vs baseline: 1.1108x; 1.1108x over previous
//
#include <hip/hip_runtime.h>

typedef __bf16 bf16x8 __attribute__((ext_vector_type(8)));
typedef float f32x4 __attribute__((ext_vector_type(4)));
typedef unsigned short u16;
typedef unsigned short u16x4 __attribute__((ext_vector_type(4)));
typedef unsigned short u16x8 __attribute__((ext_vector_type(8)));

#define MFMA16(a, b, c) __builtin_amdgcn_mfma_f32_16x16x32_bf16(a, b, c, 0, 0, 0)

__device__ __forceinline__ u16 f2bf(float f) {
    unsigned u = __builtin_bit_cast(unsigned, f);
    u += 0x7fffu + ((u >> 16) & 1u);   // RNE
    return (u16)(u >> 16);
}

__device__ __forceinline__ bf16x8 ld_frag(const u16* p) {
    u16x8 v = *(const u16x8*)p;
    return __builtin_bit_cast(bf16x8, v);
}

__device__ __forceinline__ u16x8 pack8(float4 a, float4 b) {
    u16x8 o = { f2bf(a.x), f2bf(a.y), f2bf(a.z), f2bf(a.w),
                f2bf(b.x), f2bf(b.y), f2bf(b.z), f2bf(b.w) };
    return o;
}

// async global->LDS, 16B/lane; LDS dest = wave-uniform base + lane*16
__device__ __forceinline__ void glds16(const void* g, void* l) {
    __builtin_amdgcn_global_load_lds(
        (const __attribute__((address_space(1))) unsigned int*)g,
        (__attribute__((address_space(3))) unsigned int*)l, 16, 0, 0);
}

// ---------------------------------------------------------------------------
// wcvt: Wq|Wk|Wv fp32 -> Wb bf16 in B-fragment order.
// Wb u16 off = ((nt*16 + c)*16 + f)*512 + l*8,  f = n16*2 + ks
// element = W_nt[n16*16 + (l&15)][c*64 + ks*32 + (l>>4)*8 + j]
// ---------------------------------------------------------------------------
__global__ __launch_bounds__(256) void wcvt(
    const float* __restrict__ Wq, const float* __restrict__ Wk,
    const float* __restrict__ Wv, u16* __restrict__ Wb)
{
    int g = blockIdx.x * 256 + threadIdx.x;   // 49152
    int l = g & 63;
    int f = (g >> 6) & 15;
    int c = (g >> 10) & 15;
    int nt = g >> 14;                          // 0..2
    int nrow = (f >> 1) * 16 + (l & 15);
    int k = c * 64 + (f & 1) * 32 + (l >> 4) * 8;
    const float* W = (nt == 0 ? Wq : nt == 1 ? Wk : Wv) + (size_t)nrow * 1024 + k;
    float4 a = *(const float4*)(W);
    float4 b = *(const float4*)(W + 4);
    *(u16x8*)(Wb + (size_t)g * 8) = pack8(a, b);
}

// ---------------------------------------------------------------------------
// qkv_fused: q|k|v = x @ W^T + b.  grid (3 nt, 256 m-tiles of 64).
// 768 blocks -> 3 blocks/CU (LDS 48KB pool, low VGPR).  4 waves, wave-tile
// 32m x 64n, BK=64.  A: x read 64B contiguous/thread, cvt bf16, frag-order
// LDS dbuf.  B: glds16 prefetch from Wb dbuf.  Epilogue reuses the SAME
// unified LDS pool (fixes R4's out-of-bounds alias of a smaller array).
// q stored natural [s][d]; k,v stored transposed [d][t].
// ---------------------------------------------------------------------------
__global__ __launch_bounds__(256, 3) void qkv_fused(
    const float* __restrict__ x, const u16* __restrict__ Wb,
    const float* __restrict__ bq, const float* __restrict__ bk,
    const float* __restrict__ bv,
    u16* __restrict__ qo, u16* __restrict__ kT, u16* __restrict__ vT)
{
    // unified pool, 24576 u16 = 48 KB:
    //   As bufs:  [0..4095], [4096..8191]        (8 frags x 512 each)
    //   Bs bufs:  [8192..16383], [16384..24575]  (16 frags x 512 each)
    //   epilogue: [0..9215] max — always in bounds of the one object
    __shared__ __align__(16) u16 smem[24576];

    const int nt = blockIdx.x;
    const int m0 = blockIdx.y * 64;
    const int tid = threadIdx.x, lane = tid & 63, w = tid >> 6;
    const int quad = lane >> 4, l16 = lane & 15;
    const int wm = (w >> 1) * 32, wn = (w & 1) * 64;

    // A staging map: thread -> (row rl, 16-col seg): contiguous 64B read
    const int rl = tid & 63, seg = tid >> 6;
    const float* xp = x + (size_t)(m0 + rl) * 1024 + seg * 16;
    const int af_ = (rl >> 4) * 2 + (seg >> 1);            // frag index
    const int l0 = (seg & 1) * 32 + (rl & 15);             // lane slot 0
    // B staging: wave w glds-copies frags w*4..w*4+3 of each chunk
    const u16* wb0 = Wb + ((size_t)nt * 16) * 16 * 512 + (size_t)(w * 4) * 512 + lane * 8;

    f32x4 acc[2][4] = {};

    // prologue: chunk 0 -> buf 0
    {
        #pragma unroll
        for (int j = 0; j < 4; ++j)
            glds16(wb0 + j * 512, &smem[8192 + (w * 4 + j) * 512]);
        const float4* xv = (const float4*)xp;
        *(u16x8*)&smem[af_ * 512 + l0 * 8]        = pack8(xv[0], xv[1]);
        *(u16x8*)&smem[af_ * 512 + (l0 + 16) * 8] = pack8(xv[2], xv[3]);
    }

    for (int c = 0; c < 16; ++c) {
        const int cur = c & 1, nxt = cur ^ 1;
        u16* Ac = smem + cur * 4096;
        u16* Bc = smem + 8192 + cur * 8192;
        __syncthreads();

        float4 x0, x1, x2, x3;
        if (c < 15) {   // prefetch chunk c+1: glds B (async), x to regs
            const u16* wbn = wb0 + (size_t)(c + 1) * 8192;
            u16* Bn = smem + 8192 + nxt * 8192;
            #pragma unroll
            for (int j = 0; j < 4; ++j)
                glds16(wbn + j * 512, &Bn[(w * 4 + j) * 512]);
            const float4* xv = (const float4*)(xp + (c + 1) * 64);
            x0 = xv[0]; x1 = xv[1]; x2 = xv[2]; x3 = xv[3];
        }

        // compute chunk c
        bf16x8 af[2][2], bfr[4][2];
        #pragma unroll
        for (int mi = 0; mi < 2; ++mi)
            #pragma unroll
            for (int ks = 0; ks < 2; ++ks)
                af[mi][ks] = ld_frag(&Ac[((((wm >> 4) + mi) * 2 + ks) * 64 + lane) * 8]);
        #pragma unroll
        for (int ni = 0; ni < 4; ++ni)
            #pragma unroll
            for (int ks = 0; ks < 2; ++ks)
                bfr[ni][ks] = ld_frag(&Bc[((((wn >> 4) + ni) * 2 + ks) * 64 + lane) * 8]);
        #pragma unroll
        for (int ks = 0; ks < 2; ++ks)
            #pragma unroll
            for (int mi = 0; mi < 2; ++mi)
                #pragma unroll
                for (int ni = 0; ni < 4; ++ni)
                    acc[mi][ni] = MFMA16(af[mi][ks], bfr[ni][ks], acc[mi][ni]);

        if (c < 15) {   // write A(c+1) to the other buffer
            u16* An = smem + nxt * 4096;
            *(u16x8*)&An[af_ * 512 + l0 * 8]        = pack8(x0, x1);
            *(u16x8*)&An[af_ * 512 + (l0 + 16) * 8] = pack8(x2, x3);
        }
    }

    __syncthreads();   // K-loop done; reuse pool for epilogue
    u16* Ep = smem;
    const float* bias = nt == 0 ? bq : (nt == 1 ? bk : bv);

    if (nt == 0) {
        // Ep[t][d] stride 136 (8704 u16) -> coalesced natural q store
        #pragma unroll
        for (int ni = 0; ni < 4; ++ni) {
            int d = wn + ni * 16 + l16;
            float bb = bias[d];
            #pragma unroll
            for (int mi = 0; mi < 2; ++mi)
                #pragma unroll
                for (int r = 0; r < 4; ++r)
                    Ep[(wm + mi * 16 + quad * 4 + r) * 136 + d] =
                        f2bf(acc[mi][ni][r] + bb);
        }
        __syncthreads();
        #pragma unroll
        for (int i = 0; i < 4; ++i) {
            int idx = tid + i * 256;
            int row = idx >> 4, d8 = (idx & 15) * 8;
            *(u16x8*)(qo + (size_t)(m0 + row) * 128 + d8) = *(u16x8*)&Ep[row * 136 + d8];
        }
    } else {
        // Ep[d][t] stride 72 (9216 u16) -> coalesced kT/vT[d][t] store
        u16* dstT = (nt == 1) ? kT : vT;
        #pragma unroll
        for (int ni = 0; ni < 4; ++ni) {
            int d = wn + ni * 16 + l16;
            float bb = bias[d];
            #pragma unroll
            for (int mi = 0; mi < 2; ++mi) {
                u16x4 v4 = { f2bf(acc[mi][ni][0] + bb), f2bf(acc[mi][ni][1] + bb),
                             f2bf(acc[mi][ni][2] + bb), f2bf(acc[mi][ni][3] + bb) };
                *(u16x4*)&Ep[d * 72 + wm + mi * 16 + quad * 4] = v4;
            }
        }
        __syncthreads();
        #pragma unroll
        for (int i = 0; i < 4; ++i) {
            int idx = tid + i * 256;
            int d = idx >> 3, t8 = (idx & 7) * 8;
            *(u16x8*)(dstT + (size_t)d * 16384 + m0 + t8) = *(u16x8*)&Ep[d * 72 + t8];
        }
    }
}

// ---------------------------------------------------------------------------
// kt_v: partial T[e][d] = sum_t vT[e][t]*kT[d][t] over a 128-t chunk.
// grid (32,4), 512 threads / 8 waves (wave 64e x 32d) for latency cover.
// ---------------------------------------------------------------------------
__global__ __launch_bounds__(512) void kt_v(
    const u16* __restrict__ kT, const u16* __restrict__ vT,
    float* __restrict__ part)
{
    __shared__ __align__(16) u16 vL[128 * 136];
    __shared__ __align__(16) u16 kL[128 * 136];

    const int c = blockIdx.x, b = blockIdx.y;
    const size_t g0 = (size_t)b * 4096 + c * 128;
    const int tid = threadIdx.x, lane = tid & 63, w = tid >> 6;
    const int quad = lane >> 4, l16 = lane & 15;
    const int we = (w >> 2) * 64, wd = (w & 3) * 32;

    #pragma unroll
    for (int i = 0; i < 4; ++i) {
        int idx = tid + i * 512;
        int e = idx >> 4, t8 = (idx & 15) * 8;
        *(u16x8*)&vL[e * 136 + t8] = *(const u16x8*)(vT + (size_t)e * 16384 + g0 + t8);
        *(u16x8*)&kL[e * 136 + t8] = *(const u16x8*)(kT + (size_t)e * 16384 + g0 + t8);
    }
    __syncthreads();

    f32x4 acc[4][2] = {};
    #pragma unroll
    for (int ks = 0; ks < 4; ++ks) {
        bf16x8 af[4], bfr[2];
        #pragma unroll
        for (int mi = 0; mi < 4; ++mi)
            af[mi] = ld_frag(&vL[(we + mi * 16 + l16) * 136 + ks * 32 + quad * 8]);
        #pragma unroll
        for (int ni = 0; ni < 2; ++ni)
            bfr[ni] = ld_frag(&kL[(wd + ni * 16 + l16) * 136 + ks * 32 + quad * 8]);
        #pragma unroll
        for (int mi = 0; mi < 4; ++mi)
            #pragma unroll
            for (int ni = 0; ni < 2; ++ni)
                acc[mi][ni] = MFMA16(af[mi], bfr[ni], acc[mi][ni]);
    }

    float* dst = part + (size_t)(b * 32 + c) * 16384;
    #pragma unroll
    for (int mi = 0; mi < 4; ++mi)
        #pragma unroll
        for (int ni = 0; ni < 2; ++ni)
            #pragma unroll
            for (int r = 0; r < 4; ++r)
                dst[(we + mi * 16 + quad * 4 + r) * 128 + (wd + ni * 16 + l16)] =
                    acc[mi][ni][r];
}

// ---------------------------------------------------------------------------
// reduceT: 32 fp32 partials -> T bf16 [4][128][128], scale folded in.
// ---------------------------------------------------------------------------
__global__ __launch_bounds__(256) void reduceT(
    const float* __restrict__ part, u16* __restrict__ T)
{
    int gid = blockIdx.x * 256 + threadIdx.x;   // 0..65535
    int b = gid >> 14, idx = gid & 16383;
    const float* p = part + (size_t)b * 32 * 16384 + idx;
    float s = 0.f;
    #pragma unroll
    for (int c = 0; c < 32; ++c) s += p[(size_t)c * 16384];
    T[gid] = f2bf(s * 0.088388347648318447f);   // 128^-0.5
}

// ---------------------------------------------------------------------------
// out_gemm: outT-form — C[e][s], A=T[e][d], B=q[s][d] (both d-contig).
// C/D layout gives out[s][e] as contiguous f32x4 -> full-line stores.
// grid 512 (32-s tiles, 2 blocks/CU), 4 waves: wave 64e x 16s.
// ---------------------------------------------------------------------------
__global__ __launch_bounds__(256) void out_gemm(
    const u16* __restrict__ qo, const u16* __restrict__ T,
    float* __restrict__ out)
{
    __shared__ __align__(16) u16 tL[128 * 136];
    __shared__ __align__(16) u16 qL[32 * 136];

    const int s0 = blockIdx.x * 32;
    const int b  = s0 >> 12;
    const int tid = threadIdx.x, lane = tid & 63, w = tid >> 6;
    const int quad = lane >> 4, l16 = lane & 15;
    const int we = (w >> 1) * 64, wsx = (w & 1) * 16;

    #pragma unroll
    for (int i = 0; i < 8; ++i) {
        int idx = tid + i * 256;
        int e = idx >> 4, d8 = (idx & 15) * 8;
        *(u16x8*)&tL[e * 136 + d8] = *(const u16x8*)(T + (size_t)b * 16384 + e * 128 + d8);
    }
    #pragma unroll
    for (int i = 0; i < 2; ++i) {
        int idx = tid + i * 256;
        int sr = idx >> 4, d8 = (idx & 15) * 8;
        *(u16x8*)&qL[sr * 136 + d8] = *(const u16x8*)(qo + (size_t)(s0 + sr) * 128 + d8);
    }
    __syncthreads();

    f32x4 acc[4] = {};
    #pragma unroll
    for (int ks = 0; ks < 4; ++ks) {
        bf16x8 bfr = ld_frag(&qL[(wsx + l16) * 136 + ks * 32 + quad * 8]);
        #pragma unroll
        for (int mi = 0; mi < 4; ++mi) {
            bf16x8 af = ld_frag(&tL[(we + mi * 16 + l16) * 136 + ks * 32 + quad * 8]);
            acc[mi] = MFMA16(af, bfr, acc[mi]);
        }
    }

    #pragma unroll
    for (int mi = 0; mi < 4; ++mi) {
        int s = s0 + wsx + l16;
        int e0 = we + mi * 16 + quad * 4;
        *(f32x4*)(out + (size_t)s * 128 + e0) = acc[mi];
    }
}

// ---------------------------------------------------------------------------
extern "C" void kernel_launch(void* const* d_in, const int* in_sizes, int n_in,
                              void* d_out, int out_size, void* d_ws, size_t ws_size,
                              hipStream_t stream)
{
    const float* x  = (const float*)d_in[0];
    const float* Wq = (const float*)d_in[1];
    const float* bq = (const float*)d_in[2];
    const float* Wk = (const float*)d_in[3];
    const float* bk = (const float*)d_in[4];
    const float* Wv = (const float*)d_in[5];
    const float* bv = (const float*)d_in[6];
    float* out = (float*)d_out;

    char* ws = (char*)d_ws;
    u16*   qo   = (u16*)(ws);                          //  4 MB, [s][d]
    u16*   kT   = (u16*)(ws + ((size_t)4 << 20));      //  4 MB, [d][t]
    u16*   vT   = (u16*)(ws + ((size_t)8 << 20));      //  4 MB, [e][t]
    // Wb (768 KB) aliases part (8 MB): Wb dead before kt_v writes part.
    u16*   Wb   = (u16*)(ws + ((size_t)12 << 20));
    float* part = (float*)(ws + ((size_t)12 << 20));
    u16*   T    = (u16*)(ws + ((size_t)20 << 20));     // 128 KB

    hipLaunchKernelGGL(wcvt, dim3(192), dim3(256), 0, stream, Wq, Wk, Wv, Wb);
    hipLaunchKernelGGL(qkv_fused, dim3(3, 256), dim3(256), 0, stream,
                       x, Wb, bq, bk, bv, qo, kT, vT);
    hipLaunchKernelGGL(kt_v, dim3(32, 4), dim3(512), 0, stream, kT, vT, part);
    hipLaunchKernelGGL(reduceT, dim3(256), dim3(256), 0, stream, part, T);
    hipLaunchKernelGGL(out_gemm, dim3(512), dim3(256), 0, stream, qo, T, out);
}